// Round 1
// baseline (369.636 us; speedup 1.0000x reference)
//
#include <hip/hip_runtime.h>

#define D 64

__global__ __launch_bounds__(256) void edge_scatter(
    const int* __restrict__ es, const float* __restrict__ x,
    float* __restrict__ out, int* __restrict__ count, int E) {
  int gid = blockIdx.x * blockDim.x + threadIdx.x;
  int e = gid >> 6;          // one 64-lane wave per edge
  int lane = gid & 63;
  if (e >= E) return;
  int c = es[e];             // col = es[0][e]
  int r = es[E + e];         // row = es[1][e]
  if (lane == 0) atomicAdd(&count[c], 1);
  float v = x[r * D + lane];
  // HW global_atomic_add_f32; coalesced 64 consecutive floats per wave
  unsafeAtomicAdd(&out[(size_t)c * 2 * D + lane], v);
}

__global__ __launch_bounds__(256) void finalize(
    const float* __restrict__ x, float* __restrict__ out,
    const int* __restrict__ count, int N) {
  int gid = blockIdx.x * blockDim.x + threadIdx.x;
  int node = gid >> 5;       // 32 threads/node, each owns one float4 of 128
  int j4 = gid & 31;
  if (node >= N) return;
  int cnt = count[node];
  float4* out4 = (float4*)(out + (size_t)node * 2 * D);
  if (j4 < 16) {
    // first half: sums / max(count,1)
    float4 s = out4[j4];
    float inv = 1.0f / (float)(cnt > 0 ? cnt : 1);
    s.x *= inv; s.y *= inv; s.z *= inv; s.w *= inv;
    out4[j4] = s;
  } else {
    // second half: count*x/count == x when count>0, else 0
    float4 v;
    if (cnt > 0) {
      const float4* x4 = (const float4*)(x + (size_t)node * D);
      v = x4[j4 - 16];
    } else {
      v = make_float4(0.f, 0.f, 0.f, 0.f);
    }
    out4[j4] = v;
  }
}

extern "C" void kernel_launch(void* const* d_in, const int* in_sizes, int n_in,
                              void* d_out, int out_size, void* d_ws, size_t ws_size,
                              hipStream_t stream) {
  const float* x = (const float*)d_in[0];
  const int* es = (const int*)d_in[1];
  int N = in_sizes[0] / D;
  int E = in_sizes[1] / 2;
  float* out = (float*)d_out;
  int* count = (int*)d_ws;

  hipMemsetAsync(count, 0, (size_t)N * sizeof(int), stream);
  hipMemsetAsync(out, 0, (size_t)N * 2 * D * sizeof(float), stream);

  long long escatter_threads = (long long)E * 64;
  edge_scatter<<<(int)((escatter_threads + 255) / 256), 256, 0, stream>>>(
      es, x, out, count, E);

  long long fin_threads = (long long)N * 32;
  finalize<<<(int)((fin_threads + 255) / 256), 256, 0, stream>>>(
      x, out, count, N);
}

// Round 2
// 245.283 us; speedup vs baseline: 1.5070x; 1.5070x over previous
//
#include <hip/hip_runtime.h>

#define D 64

// ---------- sort-based path ----------

__global__ __launch_bounds__(256) void hist_kernel(
    const int* __restrict__ es, int* __restrict__ count, int E) {
  int e = blockIdx.x * 256 + threadIdx.x;
  if (e < E) atomicAdd(&count[es[e]], 1);
}

// per-block exclusive scan of 1024 counts; emits block sums
__global__ __launch_bounds__(256) void scanA(
    const int* __restrict__ count, int* __restrict__ scanned,
    int* __restrict__ blocksums, int N) {
  __shared__ int lds[256];
  int t = threadIdx.x;
  int base = blockIdx.x * 1024 + t * 4;
  int v[4];
  int s = 0;
  for (int i = 0; i < 4; i++) {
    int idx = base + i;
    v[i] = (idx < N) ? count[idx] : 0;
    s += v[i];
  }
  lds[t] = s;
  __syncthreads();
  for (int off = 1; off < 256; off <<= 1) {
    int val = (t >= off) ? lds[t - off] : 0;
    __syncthreads();
    lds[t] += val;
    __syncthreads();
  }
  int run = (t == 0) ? 0 : lds[t - 1];
  for (int i = 0; i < 4; i++) {
    int idx = base + i;
    if (idx < N) scanned[idx] = run;
    run += v[i];
  }
  if (t == 255) blocksums[blockIdx.x] = lds[255];
}

// single-block exclusive scan of block sums (nb <= 128)
__global__ __launch_bounds__(128) void scanB(
    const int* __restrict__ blocksums, int* __restrict__ blockoffs, int nb) {
  __shared__ int lds[128];
  int t = threadIdx.x;
  lds[t] = (t < nb) ? blocksums[t] : 0;
  __syncthreads();
  for (int off = 1; off < 128; off <<= 1) {
    int val = (t >= off) ? lds[t - off] : 0;
    __syncthreads();
    lds[t] += val;
    __syncthreads();
  }
  if (t < nb) blockoffs[t] = (t == 0) ? 0 : lds[t - 1];
}

__global__ __launch_bounds__(256) void apply_offsets(
    const int* __restrict__ scanned, const int* __restrict__ blockoffs,
    int* __restrict__ offsets, int* __restrict__ cursor, int N) {
  int i = blockIdx.x * 256 + threadIdx.x;
  if (i < N) {
    int v = scanned[i] + blockoffs[i >> 10];
    offsets[i] = v;
    cursor[i] = v;
  }
}

__global__ __launch_bounds__(256) void scatter_rows(
    const int* __restrict__ es, int* __restrict__ cursor,
    int* __restrict__ sorted_rows, int E) {
  int e = blockIdx.x * 256 + threadIdx.x;
  if (e < E) {
    int c = es[e];
    int pos = atomicAdd(&cursor[c], 1);
    sorted_rows[pos] = es[E + e];
  }
}

// one 64-lane wave per node; lane owns one feature dim
__global__ __launch_bounds__(256) void node_reduce(
    const float* __restrict__ x, const int* __restrict__ sorted_rows,
    const int* __restrict__ offsets, const int* __restrict__ count,
    float* __restrict__ out, int N) {
  int gid = blockIdx.x * 256 + threadIdx.x;
  int node = gid >> 6;
  int lane = gid & 63;
  if (node >= N) return;
  int start = offsets[node];
  int cnt = count[node];
  float acc0 = 0.f, acc1 = 0.f;
  for (int base = 0; base < cnt; base += 64) {
    int k = base + lane;
    int r = (k < cnt) ? sorted_rows[start + k] : 0;
    int m = min(cnt - base, 64);
    int j = 0;
    for (; j + 1 < m; j += 2) {
      int r0 = __shfl(r, j);
      int r1 = __shfl(r, j + 1);
      float v0 = x[(size_t)r0 * D + lane];
      float v1 = x[(size_t)r1 * D + lane];
      acc0 += v0;
      acc1 += v1;
    }
    if (j < m) {
      int r0 = __shfl(r, j);
      acc0 += x[(size_t)r0 * D + lane];
    }
  }
  float inv = 1.0f / (float)(cnt > 0 ? cnt : 1);
  out[(size_t)node * 2 * D + lane] = (acc0 + acc1) * inv;
  out[(size_t)node * 2 * D + D + lane] =
      (cnt > 0) ? x[(size_t)node * D + lane] : 0.f;
}

// ---------- fallback atomic path (only if ws too small) ----------

__global__ __launch_bounds__(256) void edge_scatter_atomic(
    const int* __restrict__ es, const float* __restrict__ x,
    float* __restrict__ out, int* __restrict__ count, int E) {
  int gid = blockIdx.x * blockDim.x + threadIdx.x;
  int e = gid >> 6;
  int lane = gid & 63;
  if (e >= E) return;
  int c = es[e];
  int r = es[E + e];
  if (lane == 0) atomicAdd(&count[c], 1);
  float v = x[(size_t)r * D + lane];
  unsafeAtomicAdd(&out[(size_t)c * 2 * D + lane], v);
}

__global__ __launch_bounds__(256) void finalize_atomic(
    const float* __restrict__ x, float* __restrict__ out,
    const int* __restrict__ count, int N) {
  int gid = blockIdx.x * blockDim.x + threadIdx.x;
  int node = gid >> 5;
  int j4 = gid & 31;
  if (node >= N) return;
  int cnt = count[node];
  float4* out4 = (float4*)(out + (size_t)node * 2 * D);
  if (j4 < 16) {
    float4 s = out4[j4];
    float inv = 1.0f / (float)(cnt > 0 ? cnt : 1);
    s.x *= inv; s.y *= inv; s.z *= inv; s.w *= inv;
    out4[j4] = s;
  } else {
    float4 v;
    if (cnt > 0) {
      const float4* x4 = (const float4*)(x + (size_t)node * D);
      v = x4[j4 - 16];
    } else {
      v = make_float4(0.f, 0.f, 0.f, 0.f);
    }
    out4[j4] = v;
  }
}

extern "C" void kernel_launch(void* const* d_in, const int* in_sizes, int n_in,
                              void* d_out, int out_size, void* d_ws, size_t ws_size,
                              hipStream_t stream) {
  const float* x = (const float*)d_in[0];
  const int* es = (const int*)d_in[1];
  int N = in_sizes[0] / D;
  int E = in_sizes[1] / 2;
  float* out = (float*)d_out;

  size_t need = ((size_t)4 * N + 256 + E) * sizeof(int);
  if (ws_size < need) {
    // fallback: atomic path
    int* count = (int*)d_ws;
    hipMemsetAsync(count, 0, (size_t)N * sizeof(int), stream);
    hipMemsetAsync(out, 0, (size_t)N * 2 * D * sizeof(float), stream);
    long long t1 = (long long)E * 64;
    edge_scatter_atomic<<<(int)((t1 + 255) / 256), 256, 0, stream>>>(es, x, out, count, E);
    long long t2 = (long long)N * 32;
    finalize_atomic<<<(int)((t2 + 255) / 256), 256, 0, stream>>>(x, out, count, N);
    return;
  }

  int* ws = (int*)d_ws;
  int* count = ws;               // N
  int* scanned = ws + N;         // N
  int* offsets = ws + 2 * N;     // N
  int* cursor = ws + 3 * N;      // N
  int* blocksums = ws + 4 * N;   // 128
  int* blockoffs = ws + 4 * N + 128;  // 128
  int* sorted_rows = ws + 4 * N + 256;  // E

  hipMemsetAsync(count, 0, (size_t)N * sizeof(int), stream);

  hist_kernel<<<(E + 255) / 256, 256, 0, stream>>>(es, count, E);

  int nbA = (N + 1023) / 1024;
  scanA<<<nbA, 256, 0, stream>>>(count, scanned, blocksums, N);
  scanB<<<1, 128, 0, stream>>>(blocksums, blockoffs, nbA);
  apply_offsets<<<(N + 255) / 256, 256, 0, stream>>>(scanned, blockoffs, offsets, cursor, N);

  scatter_rows<<<(E + 255) / 256, 256, 0, stream>>>(es, cursor, sorted_rows, E);

  long long rt = (long long)N * 64;
  node_reduce<<<(int)((rt + 255) / 256), 256, 0, stream>>>(
      x, sorted_rows, offsets, count, out, N);
}

// Round 3
// 238.012 us; speedup vs baseline: 1.5530x; 1.0305x over previous
//
#include <hip/hip_runtime.h>

#define D 64

// ---------- sort-based path ----------

__global__ __launch_bounds__(256) void hist_kernel(
    const int* __restrict__ es, int* __restrict__ count, int E) {
  int b0 = blockIdx.x * 1024 + threadIdx.x;
#pragma unroll
  for (int k = 0; k < 4; k++) {
    int e = b0 + k * 256;
    if (e < E) atomicAdd(&count[es[e]], 1);
  }
}

// per-block exclusive scan of 1024 counts; emits block sums
__global__ __launch_bounds__(256) void scanA(
    const int* __restrict__ count, int* __restrict__ scanned,
    int* __restrict__ blocksums, int N) {
  __shared__ int lds[256];
  int t = threadIdx.x;
  int base = blockIdx.x * 1024 + t * 4;
  int v[4];
  int s = 0;
  for (int i = 0; i < 4; i++) {
    int idx = base + i;
    v[i] = (idx < N) ? count[idx] : 0;
    s += v[i];
  }
  lds[t] = s;
  __syncthreads();
  for (int off = 1; off < 256; off <<= 1) {
    int val = (t >= off) ? lds[t - off] : 0;
    __syncthreads();
    lds[t] += val;
    __syncthreads();
  }
  int run = (t == 0) ? 0 : lds[t - 1];
  for (int i = 0; i < 4; i++) {
    int idx = base + i;
    if (idx < N) scanned[idx] = run;
    run += v[i];
  }
  if (t == 255) blocksums[blockIdx.x] = lds[255];
}

// single-block exclusive scan of block sums (nb <= 128)
__global__ __launch_bounds__(128) void scanB(
    const int* __restrict__ blocksums, int* __restrict__ blockoffs, int nb) {
  __shared__ int lds[128];
  int t = threadIdx.x;
  lds[t] = (t < nb) ? blocksums[t] : 0;
  __syncthreads();
  for (int off = 1; off < 128; off <<= 1) {
    int val = (t >= off) ? lds[t - off] : 0;
    __syncthreads();
    lds[t] += val;
    __syncthreads();
  }
  if (t < nb) blockoffs[t] = (t == 0) ? 0 : lds[t - 1];
}

__global__ __launch_bounds__(256) void apply_offsets(
    const int* __restrict__ scanned, const int* __restrict__ blockoffs,
    int* __restrict__ offsets, int* __restrict__ cursor, int N, int E) {
  int i = blockIdx.x * 256 + threadIdx.x;
  if (i < N) {
    int v = scanned[i] + blockoffs[i >> 10];
    offsets[i] = v;
    cursor[i] = v;
  }
  if (i == 0) offsets[N] = E;
}

__global__ __launch_bounds__(256) void scatter_rows(
    const int* __restrict__ es, int* __restrict__ cursor,
    int* __restrict__ sorted_rows, int E) {
  int b0 = blockIdx.x * 1024 + threadIdx.x;
  int c[4], r[4], pos[4];
  bool ok[4];
#pragma unroll
  for (int k = 0; k < 4; k++) {
    int e = b0 + k * 256;
    ok[k] = (e < E);
    if (ok[k]) {
      c[k] = es[e];
      r[k] = es[E + e];
    }
  }
#pragma unroll
  for (int k = 0; k < 4; k++)
    if (ok[k]) pos[k] = atomicAdd(&cursor[c[k]], 1);
#pragma unroll
  for (int k = 0; k < 4; k++)
    if (ok[k]) sorted_rows[pos[k]] = r[k];
}

// one 64-lane wave per node; 4 lane-groups of 16, each group owns one edge,
// lane reads one float4 of the 64-float row (16 x 16B = 256B per row)
__global__ __launch_bounds__(256) void node_reduce(
    const float4* __restrict__ x4, const int* __restrict__ sorted_rows,
    const int* __restrict__ offsets, float* __restrict__ out, int N) {
  int gid = blockIdx.x * 256 + threadIdx.x;
  int node = gid >> 6;
  if (node >= N) return;
  int lane = threadIdx.x & 63;
  int eg = lane >> 4;
  int d16 = lane & 15;
  int start = offsets[node];
  int cnt = offsets[node + 1] - start;
  float4 acc = make_float4(0.f, 0.f, 0.f, 0.f);
  for (int base = 0; base < cnt; base += 4) {
    int k = base + eg;
    if (k < cnt) {
      int r = sorted_rows[start + k];
      float4 v = x4[(size_t)r * 16 + d16];
      acc.x += v.x; acc.y += v.y; acc.z += v.z; acc.w += v.w;
    }
  }
  // sum the 4 edge-groups (lanes with the same d16): xor-16 then xor-32
  acc.x += __shfl_xor(acc.x, 16); acc.y += __shfl_xor(acc.y, 16);
  acc.z += __shfl_xor(acc.z, 16); acc.w += __shfl_xor(acc.w, 16);
  acc.x += __shfl_xor(acc.x, 32); acc.y += __shfl_xor(acc.y, 32);
  acc.z += __shfl_xor(acc.z, 32); acc.w += __shfl_xor(acc.w, 32);
  float4* o4 = (float4*)(out + (size_t)node * 2 * D);
  if (eg == 0) {
    float inv = 1.0f / (float)(cnt > 0 ? cnt : 1);
    acc.x *= inv; acc.y *= inv; acc.z *= inv; acc.w *= inv;
    o4[d16] = acc;
  } else if (eg == 1) {
    float4 v = (cnt > 0) ? x4[(size_t)node * 16 + d16]
                         : make_float4(0.f, 0.f, 0.f, 0.f);
    o4[16 + d16] = v;
  }
}

// ---------- fallback atomic path (only if ws too small) ----------

__global__ __launch_bounds__(256) void edge_scatter_atomic(
    const int* __restrict__ es, const float* __restrict__ x,
    float* __restrict__ out, int* __restrict__ count, int E) {
  int gid = blockIdx.x * blockDim.x + threadIdx.x;
  int e = gid >> 6;
  int lane = gid & 63;
  if (e >= E) return;
  int c = es[e];
  int r = es[E + e];
  if (lane == 0) atomicAdd(&count[c], 1);
  float v = x[(size_t)r * D + lane];
  unsafeAtomicAdd(&out[(size_t)c * 2 * D + lane], v);
}

__global__ __launch_bounds__(256) void finalize_atomic(
    const float* __restrict__ x, float* __restrict__ out,
    const int* __restrict__ count, int N) {
  int gid = blockIdx.x * blockDim.x + threadIdx.x;
  int node = gid >> 5;
  int j4 = gid & 31;
  if (node >= N) return;
  int cnt = count[node];
  float4* out4 = (float4*)(out + (size_t)node * 2 * D);
  if (j4 < 16) {
    float4 s = out4[j4];
    float inv = 1.0f / (float)(cnt > 0 ? cnt : 1);
    s.x *= inv; s.y *= inv; s.z *= inv; s.w *= inv;
    out4[j4] = s;
  } else {
    float4 v;
    if (cnt > 0) {
      const float4* x4 = (const float4*)(x + (size_t)node * D);
      v = x4[j4 - 16];
    } else {
      v = make_float4(0.f, 0.f, 0.f, 0.f);
    }
    out4[j4] = v;
  }
}

extern "C" void kernel_launch(void* const* d_in, const int* in_sizes, int n_in,
                              void* d_out, int out_size, void* d_ws, size_t ws_size,
                              hipStream_t stream) {
  const float* x = (const float*)d_in[0];
  const int* es = (const int*)d_in[1];
  int N = in_sizes[0] / D;
  int E = in_sizes[1] / 2;
  float* out = (float*)d_out;

  size_t need = ((size_t)4 * N + 1 + 256 + E) * sizeof(int);
  if (ws_size < need) {
    int* count = (int*)d_ws;
    hipMemsetAsync(count, 0, (size_t)N * sizeof(int), stream);
    hipMemsetAsync(out, 0, (size_t)N * 2 * D * sizeof(float), stream);
    long long t1 = (long long)E * 64;
    edge_scatter_atomic<<<(int)((t1 + 255) / 256), 256, 0, stream>>>(es, x, out, count, E);
    long long t2 = (long long)N * 32;
    finalize_atomic<<<(int)((t2 + 255) / 256), 256, 0, stream>>>(x, out, count, N);
    return;
  }

  int* ws = (int*)d_ws;
  int* count = ws;                      // N
  int* scanned = ws + N;                // N
  int* offsets = ws + 2 * N;            // N+1
  int* cursor = ws + 3 * N + 1;         // N
  int* blocksums = ws + 4 * N + 1;      // 128
  int* blockoffs = ws + 4 * N + 129;    // 128
  int* sorted_rows = ws + 4 * N + 257;  // E

  hipMemsetAsync(count, 0, (size_t)N * sizeof(int), stream);

  hist_kernel<<<(E + 1023) / 1024, 256, 0, stream>>>(es, count, E);

  int nbA = (N + 1023) / 1024;
  scanA<<<nbA, 256, 0, stream>>>(count, scanned, blocksums, N);
  scanB<<<1, 128, 0, stream>>>(blocksums, blockoffs, nbA);
  apply_offsets<<<(N + 255) / 256, 256, 0, stream>>>(scanned, blockoffs, offsets, cursor, N, E);

  scatter_rows<<<(E + 1023) / 1024, 256, 0, stream>>>(es, cursor, sorted_rows, E);

  long long rt = (long long)N * 64;
  node_reduce<<<(int)((rt + 255) / 256), 256, 0, stream>>>(
      (const float4*)x, sorted_rows, offsets, out, N);
}

// Round 4
// 226.851 us; speedup vs baseline: 1.6294x; 1.0492x over previous
//
#include <hip/hip_runtime.h>

#define D 64
#define G 8  // privatized counter copies (≈ XCD count; heuristic only)

// ---------- sort-based path ----------

__global__ __launch_bounds__(256) void hist_kernel(
    const int* __restrict__ es, int* __restrict__ count_g, int N, int E) {
  int g = blockIdx.x & (G - 1);
  int* cnt = count_g + (size_t)g * N;
  int b0 = blockIdx.x * 1024 + threadIdx.x;
#pragma unroll
  for (int k = 0; k < 4; k++) {
    int e = b0 + k * 256;
    if (e < E) atomicAdd(&cnt[es[e]], 1);
  }
}

// per-block exclusive scan of 1024 total-counts; emits block sums
__global__ __launch_bounds__(256) void scanA(
    const int* __restrict__ count_g, int* __restrict__ scanned,
    int* __restrict__ blocksums, int N) {
  __shared__ int lds[256];
  int t = threadIdx.x;
  int base = blockIdx.x * 1024 + t * 4;
  int v[4];
  int s = 0;
  for (int i = 0; i < 4; i++) {
    int idx = base + i;
    int tot = 0;
    if (idx < N) {
#pragma unroll
      for (int g = 0; g < G; g++) tot += count_g[(size_t)g * N + idx];
    }
    v[i] = tot;
    s += tot;
  }
  lds[t] = s;
  __syncthreads();
  for (int off = 1; off < 256; off <<= 1) {
    int val = (t >= off) ? lds[t - off] : 0;
    __syncthreads();
    lds[t] += val;
    __syncthreads();
  }
  int run = (t == 0) ? 0 : lds[t - 1];
  for (int i = 0; i < 4; i++) {
    int idx = base + i;
    if (idx < N) scanned[idx] = run;
    run += v[i];
  }
  if (t == 255) blocksums[blockIdx.x] = lds[255];
}

// single-block exclusive scan of block sums (nb <= 256)
__global__ __launch_bounds__(256) void scanB(
    const int* __restrict__ blocksums, int* __restrict__ blockoffs, int nb) {
  __shared__ int lds[256];
  int t = threadIdx.x;
  lds[t] = (t < nb) ? blocksums[t] : 0;
  __syncthreads();
  for (int off = 1; off < 256; off <<= 1) {
    int val = (t >= off) ? lds[t - off] : 0;
    __syncthreads();
    lds[t] += val;
    __syncthreads();
  }
  if (t < nb) blockoffs[t] = (t == 0) ? 0 : lds[t - 1];
}

__global__ __launch_bounds__(256) void apply_offsets(
    const int* __restrict__ scanned, const int* __restrict__ blockoffs,
    const int* __restrict__ count_g, int* __restrict__ offsets,
    int* __restrict__ cursor_g, int N, int E) {
  int i = blockIdx.x * 256 + threadIdx.x;
  if (i < N) {
    int b = scanned[i] + blockoffs[i >> 10];
    offsets[i] = b;
#pragma unroll
    for (int g = 0; g < G; g++) {
      cursor_g[(size_t)g * N + i] = b;
      b += count_g[(size_t)g * N + i];
    }
  }
  if (i == 0) offsets[N] = E;
}

__global__ __launch_bounds__(256) void scatter_rows(
    const int* __restrict__ es, int* __restrict__ cursor_g,
    int* __restrict__ sorted_rows, int N, int E) {
  int g = blockIdx.x & (G - 1);
  int* cur = cursor_g + (size_t)g * N;
  int b0 = blockIdx.x * 1024 + threadIdx.x;
  int c[4], r[4], pos[4];
  bool ok[4];
#pragma unroll
  for (int k = 0; k < 4; k++) {
    int e = b0 + k * 256;
    ok[k] = (e < E);
    if (ok[k]) {
      c[k] = es[e];
      r[k] = es[E + e];
    }
  }
#pragma unroll
  for (int k = 0; k < 4; k++)
    if (ok[k]) pos[k] = atomicAdd(&cur[c[k]], 1);
#pragma unroll
  for (int k = 0; k < 4; k++)
    if (ok[k]) sorted_rows[pos[k]] = r[k];
}

// one 64-lane wave per node; 4 lane-groups of 16, each group owns one edge,
// lane reads one float4 of the 64-float row; 8 edges in flight (2 accs)
__global__ __launch_bounds__(256) void node_reduce(
    const float4* __restrict__ x4, const int* __restrict__ sorted_rows,
    const int* __restrict__ offsets, float* __restrict__ out, int N) {
  int gid = blockIdx.x * 256 + threadIdx.x;
  int node = gid >> 6;
  if (node >= N) return;
  int lane = threadIdx.x & 63;
  int eg = lane >> 4;
  int d16 = lane & 15;
  int start = offsets[node];
  int cnt = offsets[node + 1] - start;
  float4 acc0 = make_float4(0.f, 0.f, 0.f, 0.f);
  float4 acc1 = make_float4(0.f, 0.f, 0.f, 0.f);
  for (int base = 0; base < cnt; base += 8) {
    int k0 = base + eg;
    int k1 = base + 4 + eg;
    int r0 = (k0 < cnt) ? sorted_rows[start + k0] : -1;
    int r1 = (k1 < cnt) ? sorted_rows[start + k1] : -1;
    if (r0 >= 0) {
      float4 v = x4[(size_t)r0 * 16 + d16];
      acc0.x += v.x; acc0.y += v.y; acc0.z += v.z; acc0.w += v.w;
    }
    if (r1 >= 0) {
      float4 v = x4[(size_t)r1 * 16 + d16];
      acc1.x += v.x; acc1.y += v.y; acc1.z += v.z; acc1.w += v.w;
    }
  }
  acc0.x += acc1.x; acc0.y += acc1.y; acc0.z += acc1.z; acc0.w += acc1.w;
  // sum the 4 edge-groups (lanes with same d16): xor-16 then xor-32
  acc0.x += __shfl_xor(acc0.x, 16); acc0.y += __shfl_xor(acc0.y, 16);
  acc0.z += __shfl_xor(acc0.z, 16); acc0.w += __shfl_xor(acc0.w, 16);
  acc0.x += __shfl_xor(acc0.x, 32); acc0.y += __shfl_xor(acc0.y, 32);
  acc0.z += __shfl_xor(acc0.z, 32); acc0.w += __shfl_xor(acc0.w, 32);
  float4* o4 = (float4*)(out + (size_t)node * 2 * D);
  if (eg == 0) {
    float inv = 1.0f / (float)(cnt > 0 ? cnt : 1);
    acc0.x *= inv; acc0.y *= inv; acc0.z *= inv; acc0.w *= inv;
    o4[d16] = acc0;
  } else if (eg == 1) {
    float4 v = (cnt > 0) ? x4[(size_t)node * 16 + d16]
                         : make_float4(0.f, 0.f, 0.f, 0.f);
    o4[16 + d16] = v;
  }
}

// ---------- fallback atomic path (only if ws too small) ----------

__global__ __launch_bounds__(256) void edge_scatter_atomic(
    const int* __restrict__ es, const float* __restrict__ x,
    float* __restrict__ out, int* __restrict__ count, int E) {
  int gid = blockIdx.x * blockDim.x + threadIdx.x;
  int e = gid >> 6;
  int lane = gid & 63;
  if (e >= E) return;
  int c = es[e];
  int r = es[E + e];
  if (lane == 0) atomicAdd(&count[c], 1);
  float v = x[(size_t)r * D + lane];
  unsafeAtomicAdd(&out[(size_t)c * 2 * D + lane], v);
}

__global__ __launch_bounds__(256) void finalize_atomic(
    const float* __restrict__ x, float* __restrict__ out,
    const int* __restrict__ count, int N) {
  int gid = blockIdx.x * blockDim.x + threadIdx.x;
  int node = gid >> 5;
  int j4 = gid & 31;
  if (node >= N) return;
  int cnt = count[node];
  float4* out4 = (float4*)(out + (size_t)node * 2 * D);
  if (j4 < 16) {
    float4 s = out4[j4];
    float inv = 1.0f / (float)(cnt > 0 ? cnt : 1);
    s.x *= inv; s.y *= inv; s.z *= inv; s.w *= inv;
    out4[j4] = s;
  } else {
    float4 v;
    if (cnt > 0) {
      const float4* x4 = (const float4*)(x + (size_t)node * D);
      v = x4[j4 - 16];
    } else {
      v = make_float4(0.f, 0.f, 0.f, 0.f);
    }
    out4[j4] = v;
  }
}

extern "C" void kernel_launch(void* const* d_in, const int* in_sizes, int n_in,
                              void* d_out, int out_size, void* d_ws, size_t ws_size,
                              hipStream_t stream) {
  const float* x = (const float*)d_in[0];
  const int* es = (const int*)d_in[1];
  int N = in_sizes[0] / D;
  int E = in_sizes[1] / 2;
  float* out = (float*)d_out;

  size_t need = ((size_t)(2 * G + 2) * N + 1 + 512 + E) * sizeof(int);
  if (ws_size < need) {
    int* count = (int*)d_ws;
    hipMemsetAsync(count, 0, (size_t)N * sizeof(int), stream);
    hipMemsetAsync(out, 0, (size_t)N * 2 * D * sizeof(float), stream);
    long long t1 = (long long)E * 64;
    edge_scatter_atomic<<<(int)((t1 + 255) / 256), 256, 0, stream>>>(es, x, out, count, E);
    long long t2 = (long long)N * 32;
    finalize_atomic<<<(int)((t2 + 255) / 256), 256, 0, stream>>>(x, out, count, N);
    return;
  }

  int* ws = (int*)d_ws;
  int* count_g = ws;                          // G*N
  int* cursor_g = ws + (size_t)G * N;         // G*N
  int* scanned = ws + (size_t)2 * G * N;      // N
  int* offsets = scanned + N;                 // N+1
  int* blocksums = offsets + N + 1;           // 256
  int* blockoffs = blocksums + 256;           // 256
  int* sorted_rows = blockoffs + 256;         // E

  hipMemsetAsync(count_g, 0, (size_t)G * N * sizeof(int), stream);

  int nbE = (E + 1023) / 1024;
  hist_kernel<<<nbE, 256, 0, stream>>>(es, count_g, N, E);

  int nbA = (N + 1023) / 1024;
  scanA<<<nbA, 256, 0, stream>>>(count_g, scanned, blocksums, N);
  scanB<<<1, 256, 0, stream>>>(blocksums, blockoffs, nbA);
  apply_offsets<<<(N + 255) / 256, 256, 0, stream>>>(
      scanned, blockoffs, count_g, offsets, cursor_g, N, E);

  scatter_rows<<<nbE, 256, 0, stream>>>(es, cursor_g, sorted_rows, N, E);

  long long rt = (long long)N * 64;
  node_reduce<<<(int)((rt + 255) / 256), 256, 0, stream>>>(
      (const float4*)x, sorted_rows, offsets, out, N);
}